// Round 8
// baseline (202.407 us; speedup 1.0000x reference)
//
#include <hip/hip_runtime.h>
#include <cstdint>
#include <cstddef>

// Problem constants
#define BB 2
#define SS 2048
#define DD 1024
#define HH 16
#define HDIM 64
// Attention scale 1/sqrt(64)=0.125 and the exp->exp2 fold log2(e) are
// pre-multiplied into q at the gemm_qkv epilogue: 0.125*1.4426950 = 0.18033688.

typedef short bf16x8 __attribute__((ext_vector_type(8)));
typedef short bf16x4 __attribute__((ext_vector_type(4)));
typedef float f32x4 __attribute__((ext_vector_type(4)));
typedef float f32x2 __attribute__((ext_vector_type(2)));

union U4S8 { uint4 u; bf16x8 s; };
union U2S4 { uint2 u; bf16x4 s; unsigned short h[4]; };

#if defined(__HIP_DEVICE_COMPILE__)
# if __has_builtin(__builtin_amdgcn_exp2f)
#  define EXP2(x) __builtin_amdgcn_exp2f(x)   // bare v_exp_f32, no libm envelope
# else
#  define EXP2(x) exp2f(x)
# endif
#else
# define EXP2(x) exp2f(x)
#endif

__device__ __forceinline__ unsigned short f2bf(float f) {
    union { float f; unsigned int u; } c; c.f = f;
    unsigned int u = c.u;
    unsigned int r = (u + 0x7FFFu + ((u >> 16) & 1u)) >> 16;  // RTNE
    return (unsigned short)r;
}

// async global->LDS, 16B per lane. LDS dest must be wave-uniform base + lane*16.
__device__ __forceinline__ void async_cp16(const void* g, void* l) {
    __builtin_amdgcn_global_load_lds(
        (const __attribute__((address_space(1))) void*)g,
        (__attribute__((address_space(3))) void*)l, 16, 0, 0);
}

// ---------------------------------------------------------------- fp32 -> bf16
// One kernel for all three inputs (x:524288, w_qkv:393216, w_out:131072 uint4s).
__global__ __launch_bounds__(256) void cvt_all(
    const float* __restrict__ x, const float* __restrict__ wq,
    const float* __restrict__ wo,
    unsigned short* __restrict__ xb, unsigned short* __restrict__ wqb,
    unsigned short* __restrict__ wob) {
    int i = blockIdx.x * 256 + threadIdx.x;
    const float* in; unsigned short* out; int j;
    if (i < 524288)       { in = x;  out = xb;  j = i; }
    else if (i < 917504)  { in = wq; out = wqb; j = i - 524288; }
    else                  { in = wo; out = wob; j = i - 917504; }
    float4 a = ((const float4*)in)[2 * j];
    float4 b = ((const float4*)in)[2 * j + 1];
    union { uint4 u; unsigned short h[8]; } o;
    o.h[0] = f2bf(a.x); o.h[1] = f2bf(a.y); o.h[2] = f2bf(a.z); o.h[3] = f2bf(a.w);
    o.h[4] = f2bf(b.x); o.h[5] = f2bf(b.y); o.h[6] = f2bf(b.z); o.h[7] = f2bf(b.w);
    ((uint4*)out)[j] = o.u;
}

// ---------------------------------------------------------------- QKV GEMM
// C[m,e] = sum_d x[m,d] * w_qkv[e,d]  (NT). M=4096, N=3072, K=1024.
// r18: r17 4-phase 256x256/BK=64 with the forced lgkmcnt(0) drain REMOVED
// (compiler emits fine-grained lgkmcnt, overlapping ds_read drain with MFMA
// — r17 PMC: MfmaUtil 17%, VALU 8.5%, phase ~2040cyc vs m201's 823; the
// serial drain was the gap suspect). Quadrant order (0,0)(0,1)(1,1)(1,0):
// re-read is B-half (4 b128) not A (8) -> 28 b128/K-tile. Staging order
// matches consumption: P1=A-mh0, P2=B-nh0, P3=B-nh1, P4=A-mh1, so the
// vmcnt(4) at ends of P1/P2/P4 gives every ds_read >=1.5 phases of staging
// slack (FIFO invariant: 4 outstanding at tile entry, max 8).
//   A slots: op0=rows 0-63, op1=128-191 (mh0); op2=64-127, op3=192-255 (mh1)
//   B slots: op0={0-31,64-95}, op1={128-159,192-223} (nh0);
//            op2={32-63,96-127}, op3={160-191,224-255} (nh1)
// LDS[slot][c] = global[row(slot)][c ^ (slot&7)]  (chunk = 8 shorts = 16B).
__global__ __launch_bounds__(512, 2) void gemm_qkv(
    const unsigned short* __restrict__ A,   // x_bf   [4096][1024]
    const unsigned short* __restrict__ Bw,  // wqkv_bf[3072][1024]
    unsigned short* __restrict__ qb, unsigned short* __restrict__ kb,
    unsigned short* __restrict__ vb) {
    const int K = 1024;
    __shared__ unsigned short smem[65536];  // 128 KB: [buf][A 16384 | B 16384]
    int tid = threadIdx.x;
    int lane = tid & 63, wave = tid >> 6;
    int wmp = wave & 1, wnp = wave >> 1;
    int lm = lane & 15, lq = lane >> 4;
    int lm7 = lm & 7;

    // XCD-chunked bijective swizzle: 192 blocks = 8 XCDs x 24
    int id = blockIdx.y * 12 + blockIdx.x;
    int swz = (id & 7) * 24 + (id >> 3);
    int m0 = (swz / 12) * 256, n0 = (swz % 12) * 256;

    f32x4 acc[8][4] = {};

    // ---- staging addressing (pre-swizzled global source, linear LDS dest)
    int u = tid >> 3;                        // slot-within-op 0..63
    int csrc = ((tid & 7) ^ (u & 7)) * 8;    // swizzled source chunk (shorts)
    int sdst = tid * 8;                      // LDS dest (shorts)
    const unsigned short* gA0 = A + (size_t)(m0 + 0   + u) * K + csrc;
    const unsigned short* gA1 = A + (size_t)(m0 + 128 + u) * K + csrc;
    const unsigned short* gA2 = A + (size_t)(m0 + 64  + u) * K + csrc;
    const unsigned short* gA3 = A + (size_t)(m0 + 192 + u) * K + csrc;
    int ub = ((tid >> 8) & 1) * 64, u31 = u & 31;
    const unsigned short* gB0 = Bw + (size_t)(n0 + 0   + ub + u31) * K + csrc;
    const unsigned short* gB1 = Bw + (size_t)(n0 + 128 + ub + u31) * K + csrc;
    const unsigned short* gB2 = Bw + (size_t)(n0 + 32  + ub + u31) * K + csrc;
    const unsigned short* gB3 = Bw + (size_t)(n0 + 160 + ub + u31) * K + csrc;

#define SA0(tb, kk) async_cp16(gA0 + (kk), smem + (tb) + 0     + sdst)
#define SA1(tb, kk) async_cp16(gA1 + (kk), smem + (tb) + 4096  + sdst)
#define SA2(tb, kk) async_cp16(gA2 + (kk), smem + (tb) + 8192  + sdst)
#define SA3(tb, kk) async_cp16(gA3 + (kk), smem + (tb) + 12288 + sdst)
#define SB0(tb, kk) async_cp16(gB0 + (kk), smem + (tb) + 16384 + sdst)
#define SB1(tb, kk) async_cp16(gB1 + (kk), smem + (tb) + 20480 + sdst)
#define SB2(tb, kk) async_cp16(gB2 + (kk), smem + (tb) + 24576 + sdst)
#define SB3(tb, kk) async_cp16(gB3 + (kk), smem + (tb) + 28672 + sdst)

    // ---- fragment read addressing (swizzled chunk, conflict-free b128)
    int aBase = wmp * 4096 + lm * 64;
    int bBase = wnp * 2048 + lm * 64;
    int axk0 = (lq ^ lm7) * 8;
    int axk1 = ((4 | lq) ^ lm7) * 8;
    U4S8 af[4][2], bfr[2][2];

#define LDA(cb, mh) do { _Pragma("unroll") for (int m = 0; m < 4; m++) {            \
        af[m][0].u = *(const uint4*)(smem + (cb) + (mh) * 8192 + aBase + m * 1024 + axk0); \
        af[m][1].u = *(const uint4*)(smem + (cb) + (mh) * 8192 + aBase + m * 1024 + axk1); \
    } } while (0)
#define LDB(cb, nh) do { _Pragma("unroll") for (int n = 0; n < 2; n++) {            \
        bfr[n][0].u = *(const uint4*)(smem + (cb) + 16384 + (nh) * 8192 + bBase + n * 1024 + axk0); \
        bfr[n][1].u = *(const uint4*)(smem + (cb) + 16384 + (nh) * 8192 + bBase + n * 1024 + axk1); \
    } } while (0)
#define MM(mh, nh) do { _Pragma("unroll") for (int m = 0; m < 4; m++)               \
        _Pragma("unroll") for (int n = 0; n < 2; n++) {                             \
            acc[(mh) * 4 + m][(nh) * 2 + n] = __builtin_amdgcn_mfma_f32_16x16x32_bf16( \
                af[m][0].s, bfr[n][0].s, acc[(mh) * 4 + m][(nh) * 2 + n], 0, 0, 0); \
            acc[(mh) * 4 + m][(nh) * 2 + n] = __builtin_amdgcn_mfma_f32_16x16x32_bf16( \
                af[m][1].s, bfr[n][1].s, acc[(mh) * 4 + m][(nh) * 2 + n], 0, 0, 0); \
        } } while (0)

// One K-tile = 4 phases. Phase: {ds_read subtile | issue 2 stage ops |
// barrier | setprio(1) 16xMFMA setprio(0) | [vmcnt(4)] barrier}. NO explicit
// lgkmcnt: the compiler interleaves ds_read completion with the MFMA cluster
// (fine-grained lgkmcnt(N)), overlapping the LDS drain with compute.
// vmcnt(4) keeps 4-8 staging loads in flight across barriers; staging order
// == consumption order makes every dependency hold with >=1.5-phase slack.
#define KTILE(cb, tb, kk)                                                     \
    do {                                                                      \
        /* P1: quadrant (0,0): reads af0(8)+bf0(4); stages A-mh0(next) */     \
        LDA(cb, 0); LDB(cb, 0);                                               \
        SA0(tb, kk); SA1(tb, kk);                                             \
        __builtin_amdgcn_s_barrier();                                         \
        __builtin_amdgcn_s_setprio(1);                                        \
        MM(0, 0);                                                             \
        __builtin_amdgcn_s_setprio(0);                                        \
        asm volatile("s_waitcnt vmcnt(4)" ::: "memory");                      \
        __builtin_amdgcn_s_barrier();                                         \
        /* P2: quadrant (0,1): reads bf1(4), af0 held; stages B-nh0(next) */  \
        LDB(cb, 1);                                                           \
        SB0(tb, kk); SB1(tb, kk);                                             \
        __builtin_amdgcn_s_barrier();                                         \
        __builtin_amdgcn_s_setprio(1);                                        \
        MM(0, 1);                                                             \
        __builtin_amdgcn_s_setprio(0);                                        \
        asm volatile("s_waitcnt vmcnt(4)" ::: "memory");                      \
        __builtin_amdgcn_s_barrier();                                         \
        /* P3: quadrant (1,1): reads af1(8), bf1 held; stages B-nh1(next) */  \
        LDA(cb, 1);                                                           \
        SB2(tb, kk); SB3(tb, kk);                                             \
        __builtin_amdgcn_s_barrier();                                         \
        __builtin_amdgcn_s_setprio(1);                                        \
        MM(1, 1);                                                             \
        __builtin_amdgcn_s_setprio(0);                                        \
        __builtin_amdgcn_s_barrier();                                         \
        /* P4: quadrant (1,0): re-reads bf0(4), af1 held; stages A-mh1 */     \
        LDB(cb, 0);                                                           \
        SA2(tb, kk); SA3(tb, kk);                                             \
        __builtin_amdgcn_s_barrier();                                         \
        __builtin_amdgcn_s_setprio(1);                                        \
        MM(1, 0);                                                             \
        __builtin_amdgcn_s_setprio(0);                                        \
        asm volatile("s_waitcnt vmcnt(4)" ::: "memory");                      \
        __builtin_amdgcn_s_barrier();                                         \
    } while (0)

    // prologue: stage tile 0 in consumption order (A-mh0, B-nh0, B-nh1,
    // A-mh1); vmcnt(4) completes the oldest 4 ops (= P1's operands).
    SA0(0, 0); SA1(0, 0); SB0(0, 0); SB1(0, 0);
    SB2(0, 0); SB3(0, 0); SA2(0, 0); SA3(0, 0);
    asm volatile("s_waitcnt vmcnt(4)" ::: "memory");
    __builtin_amdgcn_s_barrier();

    #pragma unroll 1
    for (int t2 = 0; t2 < 8; ++t2) {
        int kk = t2 * 128;
        KTILE(0, 32768, kk + 64);
        KTILE(32768, 0, kk + 128);  // t2==7: over-reads one tile into adjacent ws buf
    }
#undef KTILE
#undef MM
#undef LDB
#undef LDA
#undef SA0
#undef SA1
#undef SA2
#undef SA3
#undef SB0
#undef SB1
#undef SB2
#undef SB3

    asm volatile("s_waitcnt vmcnt(0)" ::: "memory");  // drain stray over-read loads
    __builtin_amdgcn_s_barrier();                     // staging LDS done before reuse

    // Epilogue. C/D layout: col=lane&15, row=(lane>>4)*4+reg.
    // acc[mi][ni] -> C row m0+wm+mi*16+lq*4+r, col n0+wn+ni*16+lm.
    // Two 64-row chunks (mi-half) through an 8 KiB/wave LDS transpose buffer.
    unsigned short* Lw = smem + wave * 8192;  // uses 64 x 72
    int wm = wmp * 128, wn = wnp * 64;
    int b = m0 >> 11;
    int s_base = (m0 + wm) & 2047;
    int h = ((n0 + wn) >> 6) & 15;
    if (n0 < 1024) {
        // ---- v: transpose (store [B,H,HD,S]): Lw[hd][s], b64 packed writes
        unsigned short* vdst = vb + ((size_t)(b * HH + h) * HDIM) * SS;
        #pragma unroll
        for (int c = 0; c < 2; c++) {
            #pragma unroll
            for (int m4 = 0; m4 < 4; m4++)
                #pragma unroll
                for (int ni = 0; ni < 4; ni++) {
                    U2S4 t;
                    #pragma unroll
                    for (int r = 0; r < 4; r++)
                        t.h[r] = f2bf(acc[c * 4 + m4][ni][r]);
                    *(uint2*)&Lw[(ni * 16 + lm) * 72 + m4 * 16 + lq * 4] = t.u;
                }
            __builtin_amdgcn_wave_barrier();
            #pragma unroll
            for (int it = 0; it < 8; it++) {
                int hd = it * 8 + (lane >> 3);
                int so = (lane & 7) * 8;
                uint4 val = *(const uint4*)&Lw[hd * 72 + so];
                *(uint4*)(vdst + (size_t)hd * SS + s_base + c * 64 + so) = val;
            }
            __builtin_amdgcn_wave_barrier();
        }
    } else {
        // ---- q/k: gather (store [B,H,S,HD]): Lw[s][hd], no transpose
        bool isq = n0 < 2048;
        unsigned short* dst = isq ? qb : kb;
        float scale = isq ? 0.18033688f : 1.0f;  // q: fold softmax scale * log2(e)
        unsigned short* qdst = dst + ((size_t)(b * HH + h) * SS) * HDIM;
        #pragma unroll
        for (int c = 0; c < 2; c++) {
            #pragma unroll
            for (int m4 = 0; m4 < 4; m4++)
                #pragma unroll
                for (int ni = 0; ni < 4; ni++)
                    #pragma unroll
                    for (int r = 0; r < 4; r++)
                        Lw[(m4 * 16 + lq * 4 + r) * 72 + ni * 16 + lm] =
                            f2bf(acc[c * 4 + m4][ni][r] * scale);
            __builtin_amdgcn_wave_barrier();
            #pragma unroll
            for (int it = 0; it < 8; it++) {
                int srw = it * 8 + (lane >> 3);
                int so = (lane & 7) * 8;
                uint4 val = *(const uint4*)&Lw[srw * 72 + so];
                *(uint4*)(qdst + (size_t)(s_base + c * 64 + srw) * HDIM + so) = val;
            }
            __builtin_amdgcn_wave_barrier();
        }
    }
}

// ---------------------------------------------------------------- Flash attention
// r15 kernel (unchanged): 512-thr k-split blocks, async dbuf, XOR swizzle,
// K=32 PV via KAPPA-permuted K staging.
__global__ __launch_bounds__(512) void attn(
    const unsigned short* __restrict__ qb,  // [B,H,S,HD] pre-scaled (incl. log2e)
    const unsigned short* __restrict__ kb,  // [B,H,S,HD]
    const unsigned short* __restrict__ vb,  // [B,H,HD,S] (transposed)
    unsigned short* __restrict__ ob) {      // [B,S,D]
    int bh = blockIdx.y;
    int q0 = blockIdx.x * 128;
    int tid = threadIdx.x, lane = tid & 63, wave = tid >> 6;
    int grp = wave >> 2;      // k-half
    int w4  = wave & 3;       // wave-in-group: owns q rows w4*32..+31
    int lm = lane & 15, lq = lane >> 4;

    // [pair 2][KA|KB|VA|VB, 4096 shorts each] = 32768 shorts = 64 KB
    __shared__ unsigned short smem[32768];
    float* smf = (float*)smem;

    const unsigned short* qg = qb + (size_t)bh * SS * HDIM;
    const unsigned short* kg = kb + (size_t)bh * SS * HDIM;
    const unsigned short* vg = vb + (size_t)bh * HDIM * SS;

    // Q fragments (both groups load the same q rows for their k-half)
    U4S8 qf[2][2];
    #pragma unroll
    for (int qt = 0; qt < 2; qt++)
        #pragma unroll
        for (int ks = 0; ks < 2; ks++)
            qf[qt][ks].u = *(const uint4*)(
                qg + (size_t)(q0 + w4 * 32 + qt * 16 + lm) * HDIM + ks * 32 + lq * 8);

    f32x4 oacc[4][2] = {};        // O^T[hd-tile][q-subtile] (this group's k-half)
    f32x2 lsum2[2] = {};

    // ---- loop-invariant swizzled LDS read indices within a 64x64 tile (shorts)
    int lm7 = lm & 7;
    int kidx = lm * 64 + 8 * (lq ^ lm7);          // kf b128 (slot rows)
    int vidx[2];                                  // vf b128: kpos kb*32+lq*8 (true k)
    #pragma unroll
    for (int kblk = 0; kblk < 2; kblk++)
        vidx[kblk] = lm * 64 + 8 * (((kblk << 2) | lq) ^ lm7);

    // ---- staging: 512 threads x 4 async-16B = one 128-wide K-tile (K + V)
    // K source row is KAPPA-permuted: LDS slot s holds k-row kappa(s), where
    // kappa(s) = 32*(s>>5) + 8*((s>>2)&3) + 4*((s>>4)&1) + (s&3)  (s in 0..63)
    int sr  = tid >> 3;                // LDS slot row 0..63
    int s5  = sr & 31;
    int kap = (sr & 32) + (((s5 >> 2) & 3) << 3) + (((s5 >> 4) & 1) << 2) + (s5 & 3);
    int lch = (tid & 7) ^ (sr & 7);    // chunk swizzle keyed by SLOT row
    int sdst = tid * 8;                // shorts within each 4096-short region
    const unsigned short* kpA = kg + (size_t)kap * HDIM + lch * 8;   // slots 0-63
    const unsigned short* kpB = kpA + 64 * HDIM;                     // slots 64-127
    const unsigned short* vpA = vg + (size_t)sr * SS + lch * 8;      // kpos 0-63
    const unsigned short* vpB = vpA + 64;                            // kpos 64-127

    #define STAGE(pbase)                                                       \
        do {                                                                   \
            async_cp16(kpA, smem + (pbase) + sdst);                            \
            async_cp16(kpB, smem + (pbase) + 4096 + sdst);                     \
            async_cp16(vpA, smem + (pbase) + 8192 + sdst);                     \
            async_cp16(vpB, smem + (pbase) + 12288 + sdst);                    \
            kpA += 128 * HDIM; kpB += 128 * HDIM; vpA += 128; vpB += 128;      \
        } while (0)

    STAGE(0);

    for (int kt = 0; kt < SS / 128; kt += 2) {
        #pragma unroll
        for (int hf = 0; hf < 2; hf++) {
            int cbase = hf ? 16384 : 0;      // compute pair
            int obase = hf ? 0 : 16384;      // stage target pair
            __syncthreads();  // drains vmcnt: compute pair's loads landed
            STAGE(obase);  // last iter over-reads one tile into adjacent ws buf

            int kbase = cbase + grp * 4096;
            int vbase = cbase + 8192 + grp * 4096;

            // ---- S^T then P^T = 2^(S^T): tile-pair halves fill the K=32
            //      B-operand directly (kappa staging makes r-index == j)
            U4S8 pb8[2][2];   // [kblk][qt]: full 16x16x32 B-operand fragments
            #pragma unroll
            for (int mi = 0; mi < 4; mi++) {
                U4S8 kf0, kf1;
                kf0.u = *(const uint4*)(smem + kbase + mi * 1024 + kidx);
                kf1.u = *(const uint4*)(smem + kbase + mi * 1024 + (kidx ^ 32));
                #pragma unroll
                for (int qt = 0; qt < 2; qt++) {
                    f32x4 sa = {};
                    sa = __builtin_amdgcn_mfma_f32_16x16x32_bf16(kf0.s, qf[qt][0].s, sa, 0, 0, 0);
                    sa = __builtin_amdgcn_mfma_f32_16x16x32_bf16(kf1.s, qf[qt][1].s, sa, 0, 0, 0);
                    float p0 = EXP2(sa[0]);
                    float p1 = EXP2(sa[1]);
                    float p2 = EXP2(sa[2]);
                    float p3 = EXP2(sa[3]);
                    f32x2 a01; a01[0] = p0; a01[1] = p1;
                    f32x2 a23; a23[0] = p2; a23[1] = p3;
                    lsum2[qt] += a01;
                    lsum2[qt] += a23;
                    unsigned int b0 = __float_as_uint(p0) + 0x8000u;  // ties-away
                    unsigned int b1 = __float_as_uint(p1) + 0x8000u;
                    unsigned int b2 = __float_as_uint(p2) + 0x8000u;
                    unsigned int b3 = __float_as_uint(p3) + 0x8000u;
                    unsigned int lo = __builtin_amdgcn_perm(b1, b0, 0x07060302u);
                    unsigned int hi = __builtin_amdgcn_perm(b3, b2, 0x07060302u);
                    if ((mi & 1) == 0) { pb8[mi >> 1][qt].u.x = lo; pb8[mi >> 1][qt].u.y = hi; }
                    else               { pb8[mi >> 1][qt].u.z = lo; pb8[mi >> 1][qt].u.w = hi; }
                }
            }

            // ---- O^T += V^T·P^T at K=32
            #pragma unroll
            for (int mi2 = 0; mi2 < 4; mi2++) {
                #pragma unroll
                for (int kblk = 0; kblk < 2; kblk++) {
                    U4S8 vf;
                    vf.u = *(const uint4*)(smem + vbase + mi2 * 1024 + vidx[kblk]);
                    oacc[mi2][0] = __builtin_amdgcn_mfma_f32_16x16x32_bf16(
                        vf.s, pb8[kblk][0].s, oacc[mi2][0], 0, 0, 0);
                    oacc[mi2][1] = __builtin_amdgcn_mfma_f32_16x16x32_bf16(
                        vf.s, pb8[kblk][1].s, oacc[mi2][1], 0, 0, 0);
                }
            }
        }
    }
    #undef STAGE

    // ---- per-group row sums (lanes lm,+16,+32,+48 hold disjoint k partials)
    float gsum[2];
    #pragma unroll
    for (int qt = 0; qt < 2; qt++) {
        float s = lsum2[qt][0] + lsum2[qt][1];
        s += __shfl_xor(s, 16);
        s += __shfl_xor(s, 32);
        gsum[qt] = s;
    }

    __syncthreads();  // all compute done; drains stray over-read loads

    // ---- group 1 publishes raw O^T + sums (SoA: word j at j*64+lane, no conflicts)
    if (grp == 1) {
        float* pub = smf + w4 * 2048;
        #pragma unroll
        for (int mi2 = 0; mi2 < 4; mi2++)
            #pragma unroll
            for (int qt = 0; qt < 2; qt++)
                #pragma unroll
                for (int r = 0; r < 4; r++)
                    pub[(mi2 * 8 + qt * 4 + r) * 64 + lane] = oacc[mi2][qt][r];
        if (lq == 0) {
            smf[8192 + w4 * 32 + lm]      = gsum[0];
            smf[8192 + w4 * 32 + 16 + lm] = gsum[1];
        }
    }
    __syncthreads();

    // ---- group 0 combines, normalizes, writes output
    if (grp == 0) {
        float* pub = smf + w4 * 2048;
        #pragma unroll
        for (int mi2 = 0; mi2 < 4; mi2++)
            #pragma unroll
            for (int qt = 0; qt < 2; qt++)
                #pragma unroll
                for (int r = 0; r < 4; r++)
                    oacc[mi2][qt][r] += pub[(mi2 * 8 + qt * 4 + r) * 64 + lane];
        float inv[2];
        inv[0] = 1.f / (gsum[0] + smf[8192 + w4 * 32 + lm]);
        inv[1] = 1.f / (gsum[1] + smf[8192 + w4 * 32 + 16 + lm]);

        // transpose O^T back via smem (region disjoint from publish), coalesced store
        unsigned short* Ow = smem + 17024 + w4 * 2304;  // 32 x 72
        #pragma unroll
        for (int mi2 = 0; mi2 < 4; mi2++)
            #pragma unroll
            for (int qt = 0; qt < 2; qt++) {
                U2S4 t;
                #pragma unroll
                for (int r = 0; r < 4; r++)
                    t.h[r] = f2bf(oacc[mi2][qt][r] * inv[qt]);
                *(uint2*)&Ow[(qt * 16 + lm) * 72 + mi2 * 16 + lq * 4] = t.u;
            }
        __builtin_amdgcn_wave_barrier();  // Ow wave-local
        int b = bh >> 4, h = bh & 15;
        #pragma unroll
        for (int it = 0; it < 4; it++) {
            int q  = it * 8 + (lane >> 3);
            int off = (lane & 7) * 8;
            uint4 val = *(const uint4*)&Ow[q * 72 + off];
            int srw = q0 + w4 * 32 + q;
            *(uint4*)(ob + (size_t)(b * SS + srw) * DD + h * 64 + off) = val;
        }
    }
}

// ---------------------------------------------------------------- Output GEMM
// out[m,e] = sum_d o[m,d] * w_out[e,d] + b_out[e].  M=4096, N=1024, K=1024.
// 128x64 tile -> 512 blocks (2/CU). r16: BK=64 per barrier (16 barriers,
// 16 MFMA/wave/barrier — was 32 barriers x 8) + XOR-swizzled LDS.
// Buffer layout (shorts): As_k0[0,4096) As_k1[4096,8192) Bs_k0[8192,10240)
// Bs_k1[10240,12288); dbuf at +12288. Total 24576 shorts = 48 KB.
__global__ __launch_bounds__(256) void gemm_out(
    const unsigned short* __restrict__ A,   // o_bf   [4096][1024]
    const unsigned short* __restrict__ Bw,  // wout_bf[1024][1024]
    const float* __restrict__ bias, float* __restrict__ out) {
    const int K = 1024;
    __shared__ unsigned short smem[24576];
    int tid = threadIdx.x;
    int lane = tid & 63, wave = tid >> 6;
    int wm = (wave & 1) * 64, wn = (wave >> 1) * 32;
    int m0 = blockIdx.y * 128, n0 = blockIdx.x * 64;
    int lm = lane & 15, lq = lane >> 4;

    f32x4 acc[4][2] = {};

    int sdst = tid * 8;
    int lch = (tid & 3) ^ ((tid >> 3) & 3);  // swizzled source chunk
    const unsigned short* gA = A  + (size_t)(m0 + (tid >> 2)) * K + lch * 8;
    const unsigned short* gB = Bw + (size_t)(n0 + (tid >> 2)) * K + lch * 8;
    int sw = (lq ^ ((lm >> 1) & 3)) * 8;     // swizzled read chunk offset

#define OSTAGE(k0, buf) do {                                               \
        async_cp16(gA + (k0),               smem + (buf) + sdst);          \
        async_cp16(gA + 64 * K + (k0),      smem + (buf) + 2048 + sdst);   \
        async_cp16(gA + (k0) + 32,          smem + (buf) + 4096 + sdst);   \
        async_cp16(gA + 64 * K + (k0) + 32, smem + (buf) + 6144 + sdst);   \
        async_cp16(gB + (k0),               smem + (buf) + 8192 + sdst);   \
        async_cp16(gB + (k0) + 32,          smem + (buf) + 10240 + sdst);  \
    } while (0)

    OSTAGE(0, 0);
    for (int k0 = 0; k0 < K; k0 += 128) {
        #pragma unroll
        for (int hf = 0; hf < 2; hf++) {
            int base = hf ? 12288 : 0;
            int obuf = hf ? 0 : 12288;
            __syncthreads();
            int kn = k0 + 64 + hf * 64;
            if (kn < K) OSTAGE(kn, obuf);
            #pragma unroll
            for (int kc = 0; kc < 2; kc++) {
                const unsigned short* As = smem + base + kc * 4096;
                const unsigned short* Bs = smem + base + 8192 + kc * 2048;
                U4S8 af[4], bfx[2];
                #pragma unroll
                for (int i = 0; i < 4; i++)
                    af[i].u = *(const uint4*)(As + (wm + i * 16 + lm) * 32 + sw);
                #pragma unroll
                for (int i = 0; i < 2; i++)
                    bfx[i].u = *(const uint4*)(Bs + (wn + i * 16 + lm) * 32 + sw);
                #pragma unroll
                for (int mi = 0; mi < 4; mi++)
                    #pragma unroll
                    for (int ni = 0; ni < 2; ni++)
                        acc[mi][ni] = __builtin_amdgcn_mfma_f32_16x16x32_bf16(
                            af[mi].s, bfx[ni].s, acc[mi][ni], 0, 0, 0);
            }
        }
    }
#undef OSTAGE

    #pragma unroll
    for (int mi = 0; mi < 4; mi++) {
        int gr = m0 + wm + mi * 16 + lq * 4;
        #pragma unroll
        for (int ni = 0; ni < 2; ni++) {
            int gc = n0 + wn + ni * 16 + lm;
            float bv = bias[gc];
            #pragma unroll
            for (int r = 0; r < 4; r++)
                out[(size_t)(gr + r) * DD + gc] = acc[mi][ni][r] + bv;
        }
    }
}

// ---------------------------------------------------------------- launch
extern "C" void kernel_launch(void* const* d_in, const int* in_sizes, int n_in,
                              void* d_out, int out_size, void* d_ws, size_t ws_size,
                              hipStream_t stream) {
    const float* x     = (const float*)d_in[0];
    const float* w_qkv = (const float*)d_in[1];
    const float* w_out = (const float*)d_in[2];
    const float* b_out = (const float*)d_in[3];
    float* out = (float*)d_out;

    unsigned short* ws = (unsigned short*)d_ws;
    const size_t NX = (size_t)BB * SS * DD;        // 4,194,304
    unsigned short* x_bf    = ws;
    unsigned short* wqkv_bf = x_bf + NX;
    unsigned short* wout_bf = wqkv_bf + 3145728;
    unsigned short* q_buf   = wout_bf + 1048576;
    unsigned short* k_buf   = q_buf + NX;
    unsigned short* v_buf   = k_buf + NX;
    unsigned short* o_buf   = v_buf + NX;

    cvt_all<<<4096, 256, 0, stream>>>(x, w_qkv, w_out, x_bf, wqkv_bf, wout_bf);
    gemm_qkv<<<dim3(12, 16), 512, 0, stream>>>(x_bf, wqkv_bf, q_buf, k_buf, v_buf);
    attn<<<dim3(16, 32), 512, 0, stream>>>(q_buf, k_buf, v_buf, o_buf);
    gemm_out<<<dim3(16, 32), 256, 0, stream>>>(o_buf, wout_bf, b_out, out);
}

// Round 11
// 178.622 us; speedup vs baseline: 1.1332x; 1.1332x over previous
//
#include <hip/hip_runtime.h>
#include <cstdint>
#include <cstddef>

// Problem constants
#define BB 2
#define SS 2048
#define DD 1024
#define HH 16
#define HDIM 64
// Attention scale 1/sqrt(64)=0.125 and the exp->exp2 fold log2(e) are
// pre-multiplied into q at the gemm_qkv epilogue: 0.125*1.4426950 = 0.18033688.

typedef short bf16x8 __attribute__((ext_vector_type(8)));
typedef short bf16x4 __attribute__((ext_vector_type(4)));
typedef float f32x4 __attribute__((ext_vector_type(4)));
typedef float f32x2 __attribute__((ext_vector_type(2)));

union U4S8 { uint4 u; bf16x8 s; };
union U2S4 { uint2 u; bf16x4 s; unsigned short h[4]; };

#if defined(__HIP_DEVICE_COMPILE__)
# if __has_builtin(__builtin_amdgcn_exp2f)
#  define EXP2(x) __builtin_amdgcn_exp2f(x)   // bare v_exp_f32, no libm envelope
# else
#  define EXP2(x) exp2f(x)
# endif
#else
# define EXP2(x) exp2f(x)
#endif

__device__ __forceinline__ unsigned short f2bf(float f) {
    union { float f; unsigned int u; } c; c.f = f;
    unsigned int u = c.u;
    unsigned int r = (u + 0x7FFFu + ((u >> 16) & 1u)) >> 16;  // RTNE
    return (unsigned short)r;
}

// async global->LDS, 16B per lane. LDS dest must be wave-uniform base + lane*16.
__device__ __forceinline__ void async_cp16(const void* g, void* l) {
    __builtin_amdgcn_global_load_lds(
        (const __attribute__((address_space(1))) void*)g,
        (__attribute__((address_space(3))) void*)l, 16, 0, 0);
}

// ---------------------------------------------------------------- fp32 -> bf16
// One kernel for all three inputs (x:524288, w_qkv:393216, w_out:131072 uint4s).
__global__ __launch_bounds__(256) void cvt_all(
    const float* __restrict__ x, const float* __restrict__ wq,
    const float* __restrict__ wo,
    unsigned short* __restrict__ xb, unsigned short* __restrict__ wqb,
    unsigned short* __restrict__ wob) {
    int i = blockIdx.x * 256 + threadIdx.x;
    const float* in; unsigned short* out; int j;
    if (i < 524288)       { in = x;  out = xb;  j = i; }
    else if (i < 917504)  { in = wq; out = wqb; j = i - 524288; }
    else                  { in = wo; out = wob; j = i - 917504; }
    float4 a = ((const float4*)in)[2 * j];
    float4 b = ((const float4*)in)[2 * j + 1];
    union { uint4 u; unsigned short h[8]; } o;
    o.h[0] = f2bf(a.x); o.h[1] = f2bf(a.y); o.h[2] = f2bf(a.z); o.h[3] = f2bf(a.w);
    o.h[4] = f2bf(b.x); o.h[5] = f2bf(b.y); o.h[6] = f2bf(b.z); o.h[7] = f2bf(b.w);
    ((uint4*)out)[j] = o.u;
}

// ---------------------------------------------------------------- QKV GEMM
// C[m,e] = sum_d x[m,d] * w_qkv[e,d]  (NT). M=4096, N=3072, K=1024.
// r19: DEPTH, not ordering. r17 (drain) == r18 (shallow counted) == 54-55us
// proved the stall is staging-load latency with ~2-phase retire distance
// (equilibrium phase ~(560+L)/3 -> L~5k cyc). Fix: BK=32, 4-deep LDS ring
// (4 x 32KB = 128KB, same footprint), stage tile t+3 during tile t, ONE
// vmcnt(8) + ONE barrier per K-tile. A tile's 4 ops get 2-3 K-tiles of
// slack before their wait. Body free-form (12 ds_read_b128 + 4 stage +
// 32 MFMA): compiler emits fine-grained lgkm interleave (m97 evidence).
// Buffer life: buf j written for tile t+4 at t+1, read at t+4 -> both
// sides of the t+3 tile-boundary vmcnt+barrier; no intra-tile hazards.
// LDS[row][c] = global[row][c ^ (row&3)] (chunk = 8 shorts = 16B), rows
// 0-127 = op0, 128-255 = op1 (128=0 mod 4 -> same xor key, ptr+128*K).
__global__ __launch_bounds__(512, 2) void gemm_qkv(
    const unsigned short* __restrict__ A,   // x_bf   [4096][1024]
    const unsigned short* __restrict__ Bw,  // wqkv_bf[3072][1024]
    unsigned short* __restrict__ qb, unsigned short* __restrict__ kb,
    unsigned short* __restrict__ vb) {
    const int K = 1024;
    __shared__ unsigned short smem[65536];  // 128 KB: 4 bufs x [A 8192 | B 8192]
    int tid = threadIdx.x;
    int lane = tid & 63, wave = tid >> 6;
    int wmp = wave & 1, wnp = wave >> 1;
    int lm = lane & 15, lq = lane >> 4;

    // XCD-chunked bijective swizzle: 192 blocks = 8 XCDs x 24
    int id = blockIdx.y * 12 + blockIdx.x;
    int swz = (id & 7) * 24 + (id >> 3);
    int m0 = (swz / 12) * 256, n0 = (swz % 12) * 256;

    f32x4 acc[8][4] = {};

    // ---- staging addressing (pre-swizzled global source, linear LDS dest)
    int u2 = tid >> 2;                        // row-within-op 0..127
    int c2 = (tid & 3) ^ (u2 & 3);            // swizzled source chunk
    int sdst = tid * 8;                       // LDS dest (shorts)
    const unsigned short* gA0 = A  + (size_t)(m0 + u2) * K + c2 * 8;
    const unsigned short* gB0 = Bw + (size_t)(n0 + u2) * K + c2 * 8;
    const unsigned short* gA1 = gA0 + (size_t)128 * K;
    const unsigned short* gB1 = gB0 + (size_t)128 * K;

    // stage all 4 ops of one K-tile into buf j at column kk (shorts)
#define STAGE4(j, kk) do {                                                  \
        async_cp16(gA0 + (kk), smem + (j) * 16384 + 0     + sdst);          \
        async_cp16(gA1 + (kk), smem + (j) * 16384 + 4096  + sdst);          \
        async_cp16(gB0 + (kk), smem + (j) * 16384 + 8192  + sdst);          \
        async_cp16(gB1 + (kk), smem + (j) * 16384 + 12288 + sdst);          \
    } while (0)

    // ---- fragment read addressing (swizzled chunk, balanced banks)
    // A row r = wmp*128 + m*16 + lm; offset = r*32 + ((lq^(lm&3)))*8
    int axk = (lq ^ (lm & 3)) * 8;
    int aBase = (wmp * 128 + lm) * 32 + axk;
    int bBase = 8192 + (wnp * 64 + lm) * 32 + axk;
    U4S8 af[8], bfr[4];

    // One K-tile: 12 ds_read_b128 + 4 staging ops (tile t+3) + 32 MFMA +
    // vmcnt(8) (retires tile t+1's 4 ops; t+2/t+3 stay in flight) + barrier.
#define KT(j, kk3) do {                                                     \
        _Pragma("unroll")                                                   \
        for (int m = 0; m < 8; m++)                                         \
            af[m].u = *(const uint4*)(smem + (j) * 16384 + aBase + m * 512);\
        _Pragma("unroll")                                                   \
        for (int n = 0; n < 4; n++)                                         \
            bfr[n].u = *(const uint4*)(smem + (j) * 16384 + bBase + n * 512);\
        STAGE4((((j) + 3) & 3), kk3);                                       \
        _Pragma("unroll")                                                   \
        for (int m = 0; m < 8; m++)                                         \
            _Pragma("unroll")                                               \
            for (int n = 0; n < 4; n++)                                     \
                acc[m][n] = __builtin_amdgcn_mfma_f32_16x16x32_bf16(        \
                    af[m].s, bfr[n].s, acc[m][n], 0, 0, 0);                 \
        asm volatile("s_waitcnt vmcnt(8)" ::: "memory");                    \
        __builtin_amdgcn_s_barrier();                                       \
    } while (0)

    // prologue: stage tiles 0,1,2 (12 ops, tile-FIFO order); vmcnt(8)
    // retires tile 0's 4 ops before the first read.
    STAGE4(0, 0); STAGE4(1, 32); STAGE4(2, 64);
    asm volatile("s_waitcnt vmcnt(8)" ::: "memory");
    __builtin_amdgcn_s_barrier();

    // 32 K-tiles of BK=32; prefetch kk = (t+3)*32. Tail prefetches (t>=29)
    // over-read into adjacent ws buffers (never consumed, in-bounds of ws).
    #pragma unroll 1
    for (int t4 = 0; t4 < 8; ++t4) {
        int kb128 = t4 * 128;
        KT(0, kb128 + 96);
        KT(1, kb128 + 128);
        KT(2, kb128 + 160);
        KT(3, kb128 + 192);
    }
#undef KT
#undef STAGE4

    asm volatile("s_waitcnt vmcnt(0)" ::: "memory");  // drain stray over-read loads
    __builtin_amdgcn_s_barrier();                     // staging LDS done before reuse

    // Epilogue. C/D layout: col=lane&15, row=(lane>>4)*4+reg.
    // acc[mi][ni] -> C row m0+wm+mi*16+lq*4+r, col n0+wn+ni*16+lm.
    // Two 64-row chunks (mi-half) through an 8 KiB/wave LDS transpose buffer.
    unsigned short* Lw = smem + wave * 8192;  // uses 64 x 72
    int wm = wmp * 128, wn = wnp * 64;
    int b = m0 >> 11;
    int s_base = (m0 + wm) & 2047;
    int h = ((n0 + wn) >> 6) & 15;
    if (n0 < 1024) {
        // ---- v: transpose (store [B,H,HD,S]): Lw[hd][s], b64 packed writes
        unsigned short* vdst = vb + ((size_t)(b * HH + h) * HDIM) * SS;
        #pragma unroll
        for (int c = 0; c < 2; c++) {
            #pragma unroll
            for (int m4 = 0; m4 < 4; m4++)
                #pragma unroll
                for (int ni = 0; ni < 4; ni++) {
                    U2S4 t;
                    #pragma unroll
                    for (int r = 0; r < 4; r++)
                        t.h[r] = f2bf(acc[c * 4 + m4][ni][r]);
                    *(uint2*)&Lw[(ni * 16 + lm) * 72 + m4 * 16 + lq * 4] = t.u;
                }
            __builtin_amdgcn_wave_barrier();
            #pragma unroll
            for (int it = 0; it < 8; it++) {
                int hd = it * 8 + (lane >> 3);
                int so = (lane & 7) * 8;
                uint4 val = *(const uint4*)&Lw[hd * 72 + so];
                *(uint4*)(vdst + (size_t)hd * SS + s_base + c * 64 + so) = val;
            }
            __builtin_amdgcn_wave_barrier();
        }
    } else {
        // ---- q/k: gather (store [B,H,S,HD]): Lw[s][hd], no transpose
        bool isq = n0 < 2048;
        unsigned short* dst = isq ? qb : kb;
        float scale = isq ? 0.18033688f : 1.0f;  // q: fold softmax scale * log2(e)
        unsigned short* qdst = dst + ((size_t)(b * HH + h) * SS) * HDIM;
        #pragma unroll
        for (int c = 0; c < 2; c++) {
            #pragma unroll
            for (int m4 = 0; m4 < 4; m4++)
                #pragma unroll
                for (int ni = 0; ni < 4; ni++)
                    #pragma unroll
                    for (int r = 0; r < 4; r++)
                        Lw[(m4 * 16 + lq * 4 + r) * 72 + ni * 16 + lm] =
                            f2bf(acc[c * 4 + m4][ni][r] * scale);
            __builtin_amdgcn_wave_barrier();
            #pragma unroll
            for (int it = 0; it < 8; it++) {
                int srw = it * 8 + (lane >> 3);
                int so = (lane & 7) * 8;
                uint4 val = *(const uint4*)&Lw[srw * 72 + so];
                *(uint4*)(qdst + (size_t)(s_base + c * 64 + srw) * HDIM + so) = val;
            }
            __builtin_amdgcn_wave_barrier();
        }
    }
}

// ---------------------------------------------------------------- Flash attention
// r15 kernel (unchanged): 512-thr k-split blocks, async dbuf, XOR swizzle,
// K=32 PV via KAPPA-permuted K staging.
__global__ __launch_bounds__(512) void attn(
    const unsigned short* __restrict__ qb,  // [B,H,S,HD] pre-scaled (incl. log2e)
    const unsigned short* __restrict__ kb,  // [B,H,S,HD]
    const unsigned short* __restrict__ vb,  // [B,H,HD,S] (transposed)
    unsigned short* __restrict__ ob) {      // [B,S,D]
    int bh = blockIdx.y;
    int q0 = blockIdx.x * 128;
    int tid = threadIdx.x, lane = tid & 63, wave = tid >> 6;
    int grp = wave >> 2;      // k-half
    int w4  = wave & 3;       // wave-in-group: owns q rows w4*32..+31
    int lm = lane & 15, lq = lane >> 4;

    // [pair 2][KA|KB|VA|VB, 4096 shorts each] = 32768 shorts = 64 KB
    __shared__ unsigned short smem[32768];
    float* smf = (float*)smem;

    const unsigned short* qg = qb + (size_t)bh * SS * HDIM;
    const unsigned short* kg = kb + (size_t)bh * SS * HDIM;
    const unsigned short* vg = vb + (size_t)bh * HDIM * SS;

    // Q fragments (both groups load the same q rows for their k-half)
    U4S8 qf[2][2];
    #pragma unroll
    for (int qt = 0; qt < 2; qt++)
        #pragma unroll
        for (int ks = 0; ks < 2; ks++)
            qf[qt][ks].u = *(const uint4*)(
                qg + (size_t)(q0 + w4 * 32 + qt * 16 + lm) * HDIM + ks * 32 + lq * 8);

    f32x4 oacc[4][2] = {};        // O^T[hd-tile][q-subtile] (this group's k-half)
    f32x2 lsum2[2] = {};

    // ---- loop-invariant swizzled LDS read indices within a 64x64 tile (shorts)
    int lm7 = lm & 7;
    int kidx = lm * 64 + 8 * (lq ^ lm7);          // kf b128 (slot rows)
    int vidx[2];                                  // vf b128: kpos kb*32+lq*8 (true k)
    #pragma unroll
    for (int kblk = 0; kblk < 2; kblk++)
        vidx[kblk] = lm * 64 + 8 * (((kblk << 2) | lq) ^ lm7);

    // ---- staging: 512 threads x 4 async-16B = one 128-wide K-tile (K + V)
    // K source row is KAPPA-permuted: LDS slot s holds k-row kappa(s), where
    // kappa(s) = 32*(s>>5) + 8*((s>>2)&3) + 4*((s>>4)&1) + (s&3)  (s in 0..63)
    int sr  = tid >> 3;                // LDS slot row 0..63
    int s5  = sr & 31;
    int kap = (sr & 32) + (((s5 >> 2) & 3) << 3) + (((s5 >> 4) & 1) << 2) + (s5 & 3);
    int lch = (tid & 7) ^ (sr & 7);    // chunk swizzle keyed by SLOT row
    int sdst = tid * 8;                // shorts within each 4096-short region
    const unsigned short* kpA = kg + (size_t)kap * HDIM + lch * 8;   // slots 0-63
    const unsigned short* kpB = kpA + 64 * HDIM;                     // slots 64-127
    const unsigned short* vpA = vg + (size_t)sr * SS + lch * 8;      // kpos 0-63
    const unsigned short* vpB = vpA + 64;                            // kpos 64-127

    #define STAGE(pbase)                                                       \
        do {                                                                   \
            async_cp16(kpA, smem + (pbase) + sdst);                            \
            async_cp16(kpB, smem + (pbase) + 4096 + sdst);                     \
            async_cp16(vpA, smem + (pbase) + 8192 + sdst);                     \
            async_cp16(vpB, smem + (pbase) + 12288 + sdst);                    \
            kpA += 128 * HDIM; kpB += 128 * HDIM; vpA += 128; vpB += 128;      \
        } while (0)

    STAGE(0);

    for (int kt = 0; kt < SS / 128; kt += 2) {
        #pragma unroll
        for (int hf = 0; hf < 2; hf++) {
            int cbase = hf ? 16384 : 0;      // compute pair
            int obase = hf ? 0 : 16384;      // stage target pair
            __syncthreads();  // drains vmcnt: compute pair's loads landed
            STAGE(obase);  // last iter over-reads one tile into adjacent ws buf

            int kbase = cbase + grp * 4096;
            int vbase = cbase + 8192 + grp * 4096;

            // ---- S^T then P^T = 2^(S^T): tile-pair halves fill the K=32
            //      B-operand directly (kappa staging makes r-index == j)
            U4S8 pb8[2][2];   // [kblk][qt]: full 16x16x32 B-operand fragments
            #pragma unroll
            for (int mi = 0; mi < 4; mi++) {
                U4S8 kf0, kf1;
                kf0.u = *(const uint4*)(smem + kbase + mi * 1024 + kidx);
                kf1.u = *(const uint4*)(smem + kbase + mi * 1024 + (kidx ^ 32));
                #pragma unroll
                for (int qt = 0; qt < 2; qt++) {
                    f32x4 sa = {};
                    sa = __builtin_amdgcn_mfma_f32_16x16x32_bf16(kf0.s, qf[qt][0].s, sa, 0, 0, 0);
                    sa = __builtin_amdgcn_mfma_f32_16x16x32_bf16(kf1.s, qf[qt][1].s, sa, 0, 0, 0);
                    float p0 = EXP2(sa[0]);
                    float p1 = EXP2(sa[1]);
                    float p2 = EXP2(sa[2]);
                    float p3 = EXP2(sa[3]);
                    f32x2 a01; a01[0] = p0; a01[1] = p1;
                    f32x2 a23; a23[0] = p2; a23[1] = p3;
                    lsum2[qt] += a01;
                    lsum2[qt] += a23;
                    unsigned int b0 = __float_as_uint(p0) + 0x8000u;  // ties-away
                    unsigned int b1 = __float_as_uint(p1) + 0x8000u;
                    unsigned int b2 = __float_as_uint(p2) + 0x8000u;
                    unsigned int b3 = __float_as_uint(p3) + 0x8000u;
                    unsigned int lo = __builtin_amdgcn_perm(b1, b0, 0x07060302u);
                    unsigned int hi = __builtin_amdgcn_perm(b3, b2, 0x07060302u);
                    if ((mi & 1) == 0) { pb8[mi >> 1][qt].u.x = lo; pb8[mi >> 1][qt].u.y = hi; }
                    else               { pb8[mi >> 1][qt].u.z = lo; pb8[mi >> 1][qt].u.w = hi; }
                }
            }

            // ---- O^T += V^T·P^T at K=32
            #pragma unroll
            for (int mi2 = 0; mi2 < 4; mi2++) {
                #pragma unroll
                for (int kblk = 0; kblk < 2; kblk++) {
                    U4S8 vf;
                    vf.u = *(const uint4*)(smem + vbase + mi2 * 1024 + vidx[kblk]);
                    oacc[mi2][0] = __builtin_amdgcn_mfma_f32_16x16x32_bf16(
                        vf.s, pb8[kblk][0].s, oacc[mi2][0], 0, 0, 0);
                    oacc[mi2][1] = __builtin_amdgcn_mfma_f32_16x16x32_bf16(
                        vf.s, pb8[kblk][1].s, oacc[mi2][1], 0, 0, 0);
                }
            }
        }
    }
    #undef STAGE

    // ---- per-group row sums (lanes lm,+16,+32,+48 hold disjoint k partials)
    float gsum[2];
    #pragma unroll
    for (int qt = 0; qt < 2; qt++) {
        float s = lsum2[qt][0] + lsum2[qt][1];
        s += __shfl_xor(s, 16);
        s += __shfl_xor(s, 32);
        gsum[qt] = s;
    }

    __syncthreads();  // all compute done; drains stray over-read loads

    // ---- group 1 publishes raw O^T + sums (SoA: word j at j*64+lane, no conflicts)
    if (grp == 1) {
        float* pub = smf + w4 * 2048;
        #pragma unroll
        for (int mi2 = 0; mi2 < 4; mi2++)
            #pragma unroll
            for (int qt = 0; qt < 2; qt++)
                #pragma unroll
                for (int r = 0; r < 4; r++)
                    pub[(mi2 * 8 + qt * 4 + r) * 64 + lane] = oacc[mi2][qt][r];
        if (lq == 0) {
            smf[8192 + w4 * 32 + lm]      = gsum[0];
            smf[8192 + w4 * 32 + 16 + lm] = gsum[1];
        }
    }
    __syncthreads();

    // ---- group 0 combines, normalizes, writes output
    if (grp == 0) {
        float* pub = smf + w4 * 2048;
        #pragma unroll
        for (int mi2 = 0; mi2 < 4; mi2++)
            #pragma unroll
            for (int qt = 0; qt < 2; qt++)
                #pragma unroll
                for (int r = 0; r < 4; r++)
                    oacc[mi2][qt][r] += pub[(mi2 * 8 + qt * 4 + r) * 64 + lane];
        float inv[2];
        inv[0] = 1.f / (gsum[0] + smf[8192 + w4 * 32 + lm]);
        inv[1] = 1.f / (gsum[1] + smf[8192 + w4 * 32 + 16 + lm]);

        // transpose O^T back via smem (region disjoint from publish), coalesced store
        unsigned short* Ow = smem + 17024 + w4 * 2304;  // 32 x 72
        #pragma unroll
        for (int mi2 = 0; mi2 < 4; mi2++)
            #pragma unroll
            for (int qt = 0; qt < 2; qt++) {
                U2S4 t;
                #pragma unroll
                for (int r = 0; r < 4; r++)
                    t.h[r] = f2bf(oacc[mi2][qt][r] * inv[qt]);
                *(uint2*)&Ow[(qt * 16 + lm) * 72 + mi2 * 16 + lq * 4] = t.u;
            }
        __builtin_amdgcn_wave_barrier();  // Ow wave-local
        int b = bh >> 4, h = bh & 15;
        #pragma unroll
        for (int it = 0; it < 4; it++) {
            int q  = it * 8 + (lane >> 3);
            int off = (lane & 7) * 8;
            uint4 val = *(const uint4*)&Ow[q * 72 + off];
            int srw = q0 + w4 * 32 + q;
            *(uint4*)(ob + (size_t)(b * SS + srw) * DD + h * 64 + off) = val;
        }
    }
}

// ---------------------------------------------------------------- Output GEMM
// out[m,e] = sum_d o[m,d] * w_out[e,d] + b_out[e].  M=4096, N=1024, K=1024.
// 128x64 tile -> 512 blocks (2/CU). r16: BK=64 per barrier (16 barriers,
// 16 MFMA/wave/barrier — was 32 barriers x 8) + XOR-swizzled LDS.
// Buffer layout (shorts): As_k0[0,4096) As_k1[4096,8192) Bs_k0[8192,10240)
// Bs_k1[10240,12288); dbuf at +12288. Total 24576 shorts = 48 KB.
__global__ __launch_bounds__(256) void gemm_out(
    const unsigned short* __restrict__ A,   // o_bf   [4096][1024]
    const unsigned short* __restrict__ Bw,  // wout_bf[1024][1024]
    const float* __restrict__ bias, float* __restrict__ out) {
    const int K = 1024;
    __shared__ unsigned short smem[24576];
    int tid = threadIdx.x;
    int lane = tid & 63, wave = tid >> 6;
    int wm = (wave & 1) * 64, wn = (wave >> 1) * 32;
    int m0 = blockIdx.y * 128, n0 = blockIdx.x * 64;
    int lm = lane & 15, lq = lane >> 4;

    f32x4 acc[4][2] = {};

    int sdst = tid * 8;
    int lch = (tid & 3) ^ ((tid >> 3) & 3);  // swizzled source chunk
    const unsigned short* gA = A  + (size_t)(m0 + (tid >> 2)) * K + lch * 8;
    const unsigned short* gB = Bw + (size_t)(n0 + (tid >> 2)) * K + lch * 8;
    int sw = (lq ^ ((lm >> 1) & 3)) * 8;     // swizzled read chunk offset

#define OSTAGE(k0, buf) do {                                               \
        async_cp16(gA + (k0),               smem + (buf) + sdst);          \
        async_cp16(gA + 64 * K + (k0),      smem + (buf) + 2048 + sdst);   \
        async_cp16(gA + (k0) + 32,          smem + (buf) + 4096 + sdst);   \
        async_cp16(gA + 64 * K + (k0) + 32, smem + (buf) + 6144 + sdst);   \
        async_cp16(gB + (k0),               smem + (buf) + 8192 + sdst);   \
        async_cp16(gB + (k0) + 32,          smem + (buf) + 10240 + sdst);  \
    } while (0)

    OSTAGE(0, 0);
    for (int k0 = 0; k0 < K; k0 += 128) {
        #pragma unroll
        for (int hf = 0; hf < 2; hf++) {
            int base = hf ? 12288 : 0;
            int obuf = hf ? 0 : 12288;
            __syncthreads();
            int kn = k0 + 64 + hf * 64;
            if (kn < K) OSTAGE(kn, obuf);
            #pragma unroll
            for (int kc = 0; kc < 2; kc++) {
                const unsigned short* As = smem + base + kc * 4096;
                const unsigned short* Bs = smem + base + 8192 + kc * 2048;
                U4S8 af[4], bfx[2];
                #pragma unroll
                for (int i = 0; i < 4; i++)
                    af[i].u = *(const uint4*)(As + (wm + i * 16 + lm) * 32 + sw);
                #pragma unroll
                for (int i = 0; i < 2; i++)
                    bfx[i].u = *(const uint4*)(Bs + (wn + i * 16 + lm) * 32 + sw);
                #pragma unroll
                for (int mi = 0; mi < 4; mi++)
                    #pragma unroll
                    for (int ni = 0; ni < 2; ni++)
                        acc[mi][ni] = __builtin_amdgcn_mfma_f32_16x16x32_bf16(
                            af[mi].s, bfx[ni].s, acc[mi][ni], 0, 0, 0);
            }
        }
    }
#undef OSTAGE

    #pragma unroll
    for (int mi = 0; mi < 4; mi++) {
        int gr = m0 + wm + mi * 16 + lq * 4;
        #pragma unroll
        for (int ni = 0; ni < 2; ni++) {
            int gc = n0 + wn + ni * 16 + lm;
            float bv = bias[gc];
            #pragma unroll
            for (int r = 0; r < 4; r++)
                out[(size_t)(gr + r) * DD + gc] = acc[mi][ni][r] + bv;
        }
    }
}

// ---------------------------------------------------------------- launch
extern "C" void kernel_launch(void* const* d_in, const int* in_sizes, int n_in,
                              void* d_out, int out_size, void* d_ws, size_t ws_size,
                              hipStream_t stream) {
    const float* x     = (const float*)d_in[0];
    const float* w_qkv = (const float*)d_in[1];
    const float* w_out = (const float*)d_in[2];
    const float* b_out = (const float*)d_in[3];
    float* out = (float*)d_out;

    unsigned short* ws = (unsigned short*)d_ws;
    const size_t NX = (size_t)BB * SS * DD;        // 4,194,304
    unsigned short* x_bf    = ws;
    unsigned short* wqkv_bf = x_bf + NX;
    unsigned short* wout_bf = wqkv_bf + 3145728;
    unsigned short* q_buf   = wout_bf + 1048576;
    unsigned short* k_buf   = q_buf + NX;
    unsigned short* v_buf   = k_buf + NX;
    unsigned short* o_buf   = v_buf + NX;

    cvt_all<<<4096, 256, 0, stream>>>(x, w_qkv, w_out, x_bf, wqkv_bf, wout_bf);
    gemm_qkv<<<dim3(12, 16), 512, 0, stream>>>(x_bf, wqkv_bf, q_buf, k_buf, v_buf);
    attn<<<dim3(16, 32), 512, 0, stream>>>(q_buf, k_buf, v_buf, o_buf);
    gemm_out<<<dim3(16, 32), 256, 0, stream>>>(o_buf, wout_bf, b_out, out);
}